// Round 19
// baseline (39.546 us; speedup 1.0000x reference)
//
#include <hip/hip_runtime.h>

#define NSUB   10000
#define NCLS   17
#define NG     500
#define NE     80000
#define HIDN   8
#define NEG_SLOPE 0.2f

typedef __attribute__((ext_vector_type(8))) short short8;
typedef __attribute__((ext_vector_type(4))) float f32x4;

// ws layout (float units)
#define OFF_B1   0                        // 512x64 bf16 = 16384 float slots
#define OFF_B2   16384                    // 512x32 bf16 = 8192 float slots
#define OFF_D    (OFF_B2 + 8192)          // 32
#define OFF_SP   (OFF_D + 32)             // NSUB*32: {xl[8], P[17], 0 x7} per node
#define OFF_DP   (OFF_SP + NSUB*32)       // NSUB*32: {xr[8], logP[17], 0 x7} per node
#define OFF_NUM  (OFF_DP + NSUB*32)       // NSUB
#define OFF_DEN  (OFF_NUM + NSUB)         // NSUB
#define OFF_LLP  (OFF_DEN + NSUB)         // 625 per-tile ll partials (plain stores)
#define OFF_PF   (OFF_LLP + 640)          // 256 prefetch anti-DCE slots

__device__ __forceinline__ unsigned short f2bf(float f) {
    unsigned u = __float_as_uint(f);
    u += 0x7FFFu + ((u >> 16) & 1u);      // round-to-nearest-even
    return (unsigned short)(u >> 16);
}

#define MFMA16 __builtin_amdgcn_mfma_f32_16x16x32_bf16

// ---- prep v3: round-14 build + D + zeroing + x L3-PREFETCH blocks ----
// The harness's 256MB poison fill evicts x from L3 between replays; k_cell's
// cold x reads cost ~10us (round-16 cold-vs-warm measurement). Blocks >= 112
// stream all of x (20MB) at HBM BW during prep, warming the 256MB L3 so
// k_cell's reads are L3 hits.
__global__ void k_prep(const float* __restrict__ Mu, const float* __restrict__ Var,
                       const float* __restrict__ Wl, const float* __restrict__ Wr,
                       const float* __restrict__ x,
                       unsigned short* __restrict__ B1, unsigned short* __restrict__ B2,
                       float* __restrict__ D, float* __restrict__ zeroBase,
                       float* __restrict__ out, float* __restrict__ pfS) {
    const int b = blockIdx.x;
    const int tid = threadIdx.x;
    if (b < 16) {
        const int ks = b;
        __shared__ float sMu[NCLS][33], sVa[NCLS][33];
        __shared__ float sWl[32][8], sWr[32][8];
        for (int t = tid; t < NCLS * 32; t += 256) {
            const int c = t >> 5, gg = t & 31;
            const int g = ks * 32 + gg;
            sMu[c][gg] = (g < NG) ? Mu[c * NG + g] : 0.f;
            sVa[c][gg] = (g < NG) ? Var[c * NG + g] : 1.f;
        }
        {
            const int gg = tid >> 3, h = tid & 7;
            const int g = ks * 32 + gg;
            sWl[gg][h] = (g < NG) ? Wl[g * HIDN + h] : 0.f;
            sWr[gg][h] = (g < NG) ? Wr[g * HIDN + h] : 0.f;
        }
        __syncthreads();
        if (tid < 64) {
            const int lane = tid;
            const int fgrp = lane >> 4, fj = lane & 15;
            unsigned short v1[4][8], v2[2][8];
            #pragma unroll
            for (int e = 0; e < 8; e++) {
                const int gg = fgrp * 8 + e;
                const bool gv = (ks * 32 + gg < NG);
                #pragma unroll
                for (int nt = 0; nt < 4; nt++) {
                    const int col = nt * 16 + fj;
                    float v = 0.f;
                    if (gv) {
                        if (col >= 17 && col < 34)      v = sMu[col - 17][gg] / sVa[col - 17][gg];
                        else if (col >= 34 && col < 42) v = sWl[gg][col - 34];
                        else if (col >= 42 && col < 50) v = sWr[gg][col - 42];
                    }
                    v1[nt][e] = f2bf(v);
                }
                #pragma unroll
                for (int nt = 0; nt < 2; nt++) {
                    const int col = nt * 16 + fj;
                    float v = 0.f;
                    if (gv && col < NCLS) v = 1.0f / sVa[col][gg];
                    v2[nt][e] = f2bf(v);
                }
            }
            #pragma unroll
            for (int nt = 0; nt < 4; nt++)
                *reinterpret_cast<short8*>(B1 + (size_t)((ks * 4 + nt) * 64 + lane) * 8) =
                    *reinterpret_cast<short8*>(v1[nt]);
            #pragma unroll
            for (int nt = 0; nt < 2; nt++)
                *reinterpret_cast<short8*>(B2 + (size_t)((ks * 2 + nt) * 64 + lane) * 8) =
                    *reinterpret_cast<short8*>(v2[nt]);
        }
    } else if (b < 33) {
        const int c = b - 16;
        float s = 0.f;
        for (int g = tid; g < NG; g += 256) {
            const float m = Mu[c * NG + g];
            s += m * m / Var[c * NG + g];
        }
        __shared__ float red[4];
        #pragma unroll
        for (int o = 32; o; o >>= 1) s += __shfl_xor(s, o);
        const int w = tid >> 6, l = tid & 63;
        if (l == 0) red[w] = s;
        __syncthreads();
        if (tid == 0) D[c] = red[0] + red[1] + red[2] + red[3];
    } else if (b < 112) {
        const int i = (b - 33) * 256 + tid;           // zero NUM/DEN (2*NSUB)
        if (i < 2 * NSUB) zeroBase[i] = 0.f;
        if (b == 33 && tid < 2) out[tid] = 0.f;
    } else {
        // prefetch x into L3: 1,250,000 float4 over 256 blocks, grid-strided
        const int pb = b - 112;                       // 0..255
        const float4* x4 = reinterpret_cast<const float4*>(x);
        float acc = 0.f;
        for (int i = pb * 256 + tid; i < (NSUB * NG) / 4; i += 256 * 256) {
            const float4 v = x4[i];
            acc += v.x + v.y + v.z + v.w;
        }
        #pragma unroll
        for (int o = 32; o; o >>= 1) acc += __shfl_xor(acc, o);
        if ((tid & 63) == 0) pfS[pb] = acc;           // plain store: keeps loads live
    }
}

// ---- per-cell: round-18 (GEMM + parallel epilogue, no hot atomic) ----
__launch_bounds__(256)
__global__ void k_cell(const float* __restrict__ x, const int* __restrict__ sidx,
                       const float* __restrict__ Wp, const float* __restrict__ Sp,
                       const float* __restrict__ blv, const float* __restrict__ brv,
                       const unsigned short* __restrict__ B1,
                       const unsigned short* __restrict__ B2,
                       const float* __restrict__ D,
                       float* __restrict__ out, float* __restrict__ SP,
                       float* __restrict__ DP, float* __restrict__ LLPART) {
    const int tid = threadIdx.x;
    const int w = tid >> 6, l = tid & 63;
    const int grp = l >> 4, j = l & 15;
    const int rowbase = blockIdx.x * 16;             // 625 tiles exactly

    f32x4 a0 = {0,0,0,0}, a1 = {0,0,0,0}, a2 = {0,0,0,0}, a3 = {0,0,0,0};
    const float* xr = x + (size_t)(rowbase + j) * NG;
    const short8* b1 = reinterpret_cast<const short8*>(B1);
    const short8* b2 = reinterpret_cast<const short8*>(B2);

#define KSTEP(ks, fa, fb)                                                \
    {                                                                    \
        const short8* p1 = b1 + (size_t)((ks) * 4) * 64 + l;             \
        const short8* p2 = b2 + (size_t)((ks) * 2) * 64 + l;             \
        a0 = MFMA16(fa, p1[0],   a0, 0, 0, 0);                           \
        a1 = MFMA16(fa, p1[64],  a1, 0, 0, 0);                           \
        a2 = MFMA16(fa, p1[128], a2, 0, 0, 0);                           \
        a3 = MFMA16(fa, p1[192], a3, 0, 0, 0);                           \
        a0 = MFMA16(fb, p2[0],   a0, 0, 0, 0);                           \
        a1 = MFMA16(fb, p2[64],  a1, 0, 0, 0);                           \
    }

    const int ks0 = w * 4;
    #pragma unroll
    for (int i = 0; i < 3; i++) {
        const int ks = ks0 + i;
        const int g0 = ks * 32 + grp * 8;
        const float4 v0 = *reinterpret_cast<const float4*>(xr + g0);
        const float4 v1 = *reinterpret_cast<const float4*>(xr + g0 + 4);
        const float xv[8] = { v0.x, v0.y, v0.z, v0.w, v1.x, v1.y, v1.z, v1.w };
        short8 fa, fb;
        #pragma unroll
        for (int e = 0; e < 8; e++) { fa[e] = (short)f2bf(xv[e]); fb[e] = (short)f2bf(xv[e] * xv[e]); }
        KSTEP(ks, fa, fb);
    }
    if (w < 3) {
        const int ks = ks0 + 3;
        const int g0 = ks * 32 + grp * 8;
        const float4 v0 = *reinterpret_cast<const float4*>(xr + g0);
        const float4 v1 = *reinterpret_cast<const float4*>(xr + g0 + 4);
        const float xv[8] = { v0.x, v0.y, v0.z, v0.w, v1.x, v1.y, v1.z, v1.w };
        short8 fa, fb;
        #pragma unroll
        for (int e = 0; e < 8; e++) { fa[e] = (short)f2bf(xv[e]); fb[e] = (short)f2bf(xv[e] * xv[e]); }
        KSTEP(ks, fa, fb);
    } else {                                         // ks = 15 tail: genes 480..499 valid
        const int g0 = 480 + grp * 8;
        float4 v0 = {0,0,0,0}, v1 = {0,0,0,0};
        if (g0 <= 496) v0 = *reinterpret_cast<const float4*>(xr + g0);
        if (g0 <= 488) v1 = *reinterpret_cast<const float4*>(xr + g0 + 4);
        const float xv[8] = { v0.x, v0.y, v0.z, v0.w, v1.x, v1.y, v1.z, v1.w };
        short8 fa, fb;
        #pragma unroll
        for (int e = 0; e < 8; e++) { fa[e] = (short)f2bf(xv[e]); fb[e] = (short)f2bf(xv[e] * xv[e]); }
        KSTEP(15, fa, fb);
    }
#undef KSTEP

    // C layout: row = grp*4 + r, col = nt*16 + j (m89-verified)
    __shared__ float ct[4][16][68];
    #pragma unroll
    for (int r = 0; r < 4; r++) {
        ct[w][grp * 4 + r][j]      = a0[r];
        ct[w][grp * 4 + r][16 + j] = a1[r];
        ct[w][grp * 4 + r][32 + j] = a2[r];
        ct[w][grp * 4 + r][48 + j] = a3[r];
    }
    __syncthreads();

    if (w == 0) {
        const int cl = l & 15;                        // cell within tile
        const int r  = l >> 4;                        // class-replica 0..3
        const int cell = rowbase + cl;
        const int idx  = sidx[cell];
        const float s  = Sp[idx];
        const float* wrow = Wp + (size_t)idx * NCLS;

        float p[4];
        #pragma unroll
        for (int k = 0; k < 4; k++) p[k] = wrow[4 * r + k];
        const float p16raw = (r == 3) ? wrow[16] : -1e30f;

        float mx = fmaxf(fmaxf(p[0], p[1]), fmaxf(p[2], p[3]));
        mx = fmaxf(mx, p16raw);
        mx = fmaxf(mx, __shfl_xor(mx, 16));
        mx = fmaxf(mx, __shfl_xor(mx, 32));

        float sum = 0.f;
        #pragma unroll
        for (int k = 0; k < 4; k++) { p[k] = __expf(p[k] - mx); sum += p[k]; }
        float p16 = (r == 3) ? __expf(p16raw - mx) : 0.f;
        sum += p16;
        sum += __shfl_xor(sum, 16);
        sum += __shfl_xor(sum, 32);
        const float inv = 1.0f / sum;

        float* orow = out + 2 + (size_t)cell * NCLS;
        float* sp   = SP + (size_t)cell * 32;
        float* dp   = DP + (size_t)cell * 32;

        float llp = 0.f;
        #pragma unroll
        for (int k = 0; k < 4; k++) {
            const int c = 4 * r + k;
            p[k] *= inv;
            const float lg = __logf(p[k] + 1e-8f);
            orow[c]   = p[k];
            sp[8 + c] = p[k];
            dp[8 + c] = lg;
            const float T1 = ct[0][cl][c] + ct[1][cl][c] + ct[2][cl][c] + ct[3][cl][c];
            const float T2 = ct[0][cl][NCLS + c] + ct[1][cl][NCLS + c]
                           + ct[2][cl][NCLS + c] + ct[3][cl][NCLS + c];
            llp += p[k] * (-0.5f * T1 + s * T2 - 0.5f * s * s * D[c]);
        }
        if (r == 3) {                                 // class 16
            p16 *= inv;
            const float lg = __logf(p16 + 1e-8f);
            orow[16]   = p16;
            sp[8 + 16] = p16;
            dp[8 + 16] = lg;
            const float T1 = ct[0][cl][16] + ct[1][cl][16] + ct[2][cl][16] + ct[3][cl][16];
            const float T2 = ct[0][cl][NCLS + 16] + ct[1][cl][NCLS + 16]
                           + ct[2][cl][NCLS + 16] + ct[3][cl][NCLS + 16];
            llp += p16 * (-0.5f * T1 + s * T2 - 0.5f * s * s * D[16]);
        }

        if (r == 1 || r == 2) {
            #pragma unroll
            for (int k = 0; k < 4; k++) {
                const int h = (r - 1) * 4 + k;
                sp[h] = ct[0][cl][34 + h] + ct[1][cl][34 + h]
                      + ct[2][cl][34 + h] + ct[3][cl][34 + h] + blv[h];
                dp[h] = ct[0][cl][42 + h] + ct[1][cl][42 + h]
                      + ct[2][cl][42 + h] + ct[3][cl][42 + h] + brv[h];
            }
        }
        if (r == 0) {
            #pragma unroll
            for (int k = 0; k < 4; k++) { sp[25 + k] = 0.f; dp[25 + k] = 0.f; }
        } else if (r == 1) {
            #pragma unroll
            for (int k = 0; k < 3; k++) { sp[29 + k] = 0.f; dp[29 + k] = 0.f; }
        }

        float llv = llp;
        #pragma unroll
        for (int o = 32; o; o >>= 1) llv += __shfl_xor(llv, o);
        if (l == 0) LLPART[blockIdx.x] = llv;
    }
}

// ---- fused edge pass: 2-line packed gathers per side, no max-shift ----
__global__ void k_edge(const int* __restrict__ ei, const float* __restrict__ att,
                       const float* __restrict__ SP, const float* __restrict__ DP,
                       float* __restrict__ NUM, float* __restrict__ DEN) {
    const int k = blockIdx.x * 256 + threadIdx.x;
    if (k >= NE) return;
    const int s = ei[k], d = ei[NE + k];
    const float4* sp = reinterpret_cast<const float4*>(SP + (size_t)s * 32);
    const float4* dp = reinterpret_cast<const float4*>(DP + (size_t)d * 32);
    const float4 xa0 = sp[0], xa1 = sp[1];
    const float4 xb0 = dp[0], xb1 = dp[1];
    const float hv[8] = { xa0.x + xb0.x, xa0.y + xb0.y, xa0.z + xb0.z, xa0.w + xb0.w,
                          xa1.x + xb1.x, xa1.y + xb1.y, xa1.z + xb1.z, xa1.w + xb1.w };
    float e = 0.f;
    #pragma unroll
    for (int h = 0; h < HIDN; h++) {
        const float v = hv[h];
        e += ((v > 0.f) ? v : NEG_SLOPE * v) * att[h];
    }
    const float ex = __expf(e);            // no max-shift: |e| <~ 8, exp in f32 range
    float wgt = 0.f;
    #pragma unroll
    for (int q = 2; q < 7; q++) {          // P[17]+pad dot logP[17]+pad
        const float4 ps = sp[q];
        const float4 ld = dp[q];
        wgt += ps.x * ld.x + ps.y * ld.y + ps.z * ld.z + ps.w * ld.w;
    }
    atomicAdd(NUM + d, ex * wgt);
    atomicAdd(DEN + d, ex);
}

// ---- node pass: ce_space sum + LLPART fold ----
__global__ void k_node(const float* __restrict__ NUM, const float* __restrict__ DEN,
                       const float* __restrict__ LLPART, float* __restrict__ out) {
    const int n = blockIdx.x * 256 + threadIdx.x;
    float v = 0.f, vll = 0.f;
    if (n < NSUB) {
        const float dd = DEN[n];
        if (dd > 0.f) v = NUM[n] / dd;
    }
    if (n < 625) vll = LLPART[n];
    #pragma unroll
    for (int o = 32; o; o >>= 1) { v += __shfl_xor(v, o); vll += __shfl_xor(vll, o); }
    if ((threadIdx.x & 63) == 0) {
        if (v != 0.f)   atomicAdd(out + 1, -v * (1.0f / NSUB));
        if (vll != 0.f) atomicAdd(out,     vll * (1.0f / NSUB));
    }
}

extern "C" void kernel_launch(void* const* d_in, const int* in_sizes, int n_in,
                              void* d_out, int out_size, void* d_ws, size_t ws_size,
                              hipStream_t stream) {
    const float* x    = (const float*)d_in[0];
    const float* Mu   = (const float*)d_in[1];
    const float* Var  = (const float*)d_in[2];
    const int*   ei   = (const int*)d_in[3];
    const int*   sidx = (const int*)d_in[4];
    const float* Wp   = (const float*)d_in[5];
    const float* Sp   = (const float*)d_in[6];
    const float* Wl   = (const float*)d_in[7];
    const float* bl   = (const float*)d_in[8];
    const float* Wr   = (const float*)d_in[9];
    const float* br   = (const float*)d_in[10];
    const float* att  = (const float*)d_in[11];
    float* out = (float*)d_out;
    float* ws  = (float*)d_ws;

    unsigned short* B1 = (unsigned short*)(ws + OFF_B1);
    unsigned short* B2 = (unsigned short*)(ws + OFF_B2);
    float* D    = ws + OFF_D;
    float* SP   = ws + OFF_SP;
    float* DP   = ws + OFF_DP;
    float* NUM  = ws + OFF_NUM;
    float* DEN  = ws + OFF_DEN;
    float* LLP  = ws + OFF_LLP;
    float* PF   = ws + OFF_PF;

    (void)in_sizes; (void)n_in; (void)out_size; (void)ws_size;

    // 16 (frag) + 17 (D) + 79 (zeroing) + 256 (x prefetch) = 368 blocks
    k_prep<<<368, 256, 0, stream>>>(Mu, Var, Wl, Wr, x, B1, B2, D, NUM, out, PF);
    k_cell<<<NSUB / 16, 256, 0, stream>>>(x, sidx, Wp, Sp, bl, br, B1, B2, D,
                                          out, SP, DP, LLP);
    k_edge<<<(NE + 255) / 256, 256, 0, stream>>>(ei, att, SP, DP, NUM, DEN);
    k_node<<<(NSUB + 255) / 256, 256, 0, stream>>>(NUM, DEN, LLP, out);
}